// Round 17
// baseline (1347.790 us; speedup 1.0000x reference)
//
#include <hip/hip_runtime.h>
#include <hip/hip_bf16.h>

// ModulatedConv2d b=16, ic=oc=512, k=3, h=w=64.
// R17: R16 with the tail off-by-one FIXED (step CH=14 must load A(143);
// R16 skipped it -> stale aP[1] -> absmax 0.906). Design unchanged:
// A-fragments DIRECT from global (16 fully-used 64B lines/instr, L1-shared
// x4 waves), prefetched 1 step ahead into ping-pong regs. LDS holds ONLY B
// (ring-4, 64KB): LDS traffic/K-step 128KB -> 48KB. One barrier/step,
// vmw<2> counted ledger (audited: B(kk+1) >= 10 ops old at its barrier).

typedef __bf16 bf16x8 __attribute__((ext_vector_type(8)));
typedef float  f32x4  __attribute__((ext_vector_type(4)));

#define IC   512
#define OC   512
#define HW   4096
#define KTOT 4608

typedef __attribute__((address_space(3))) unsigned lds_u32;
typedef const __attribute__((address_space(1))) unsigned glb_u32;
#define GLL16(gsrc, ldst) \
    __builtin_amdgcn_global_load_lds((glb_u32*)(gsrc), (lds_u32*)(ldst), 16, 0, 0)
#define BAR()   asm volatile("s_barrier" ::: "memory")

template<int N> __device__ __forceinline__ void vmw() {
    asm volatile("s_waitcnt vmcnt(%0)" :: "n"(N) : "memory");
}

#define MFMA1(A, B, C) __builtin_amdgcn_mfma_f32_16x16x32_bf16(A, B, C, 0, 0, 0)

// ---------------- kernel 1: style modulation s[b][i] ----------------
__global__ __launch_bounds__(256) void style_mod_kernel(
    const float* __restrict__ style, const float* __restrict__ mod_w,
    const float* __restrict__ mod_b, float* __restrict__ s_out)
{
    int pair = blockIdx.x * 4 + (threadIdx.x >> 6);
    int lane = threadIdx.x & 63;
    int b = pair >> 9;
    int i = pair & 511;
    const float4* sv = (const float4*)(style + b * 512);
    const float4* wv = (const float4*)(mod_w + i * 512);
    float4 a0 = sv[lane * 2], a1 = sv[lane * 2 + 1];
    float4 w0 = wv[lane * 2], w1 = wv[lane * 2 + 1];
    float sum = a0.x*w0.x + a0.y*w0.y + a0.z*w0.z + a0.w*w0.w
              + a1.x*w1.x + a1.y*w1.y + a1.z*w1.z + a1.w*w1.w;
    #pragma unroll
    for (int off = 32; off; off >>= 1) sum += __shfl_xor(sum, off);
    if (lane == 0) s_out[pair] = sum + mod_b[i];
}

// ------------- kernel 2: demod + bf16 wmod, block per oc -------------
__global__ __launch_bounds__(256) void wmod_kernel(
    const float* __restrict__ weight,   // [512][4608] (e = ic*9+tap)
    const float* __restrict__ s_in,     // [16][512]
    __hip_bfloat16* __restrict__ wmod)  // [16*512][4608] (e' = tap*512+ic)
{
    int oc = blockIdx.x;
    __shared__ float w_sh[4608];
    __shared__ float s_sh[8192];
    __shared__ float q_sh[512];
    __shared__ float demod_sh[16];
    int t = threadIdx.x;
    const float* wrow = weight + (size_t)oc * KTOT;
    for (int e = t; e < 4608; e += 256) w_sh[e] = wrow[e];
    for (int e = t; e < 8192; e += 256) s_sh[e] = s_in[e];
    __syncthreads();
    for (int ic = t; ic < 512; ic += 256) {
        float q = 0.f;
        #pragma unroll
        for (int tap = 0; tap < 9; ++tap) { float w = w_sh[ic * 9 + tap]; q += w * w; }
        q_sh[ic] = q;
    }
    __syncthreads();
    int bb = t >> 4, li = t & 15;
    float part = 0.f;
    for (int ic = li; ic < 512; ic += 16) {
        float sv = s_sh[bb * 512 + ic];
        part += q_sh[ic] * sv * sv;
    }
    #pragma unroll
    for (int off = 8; off; off >>= 1) part += __shfl_xor(part, off, 16);
    if (li == 0) demod_sh[bb] = rsqrtf(part + 1e-8f);
    __syncthreads();
    for (int b2 = 0; b2 < 16; ++b2) {
        float dm = demod_sh[b2];
        const float* srow = s_sh + b2 * 512;
        __hip_bfloat16* dst = wmod + ((size_t)b2 * 512 + oc) * KTOT;
        for (int ep = t; ep < 4608; ep += 256) {
            int tap = ep >> 9, ic = ep & 511;
            dst[ep] = __float2bfloat16(w_sh[ic * 9 + tap] * srow[ic] * dm);
        }
    }
}

// ------------- kernel 3a: zero pad row of xT -------------
__global__ void zero_row_kernel(__hip_bfloat16* xT) {
    ((unsigned*)(xT + ((size_t)blockIdx.x * 4097 + 4096) * 512))[threadIdx.x] = 0u;
}

// ------------- kernel 3b: x [b][ic][pix] f32 -> xT [b][pix][ic] bf16 -------------
__global__ __launch_bounds__(256) void xpose_kernel(
    const float* __restrict__ x, __hip_bfloat16* __restrict__ xT)
{
    __shared__ __align__(16) float tile[64][68];
    int b = blockIdx.z, ic0 = blockIdx.y * 64, p0 = blockIdx.x * 64;
    int t = threadIdx.x;
    const float* xb = x + ((size_t)b * 512 + ic0) * 4096 + p0;
    int rr = t >> 4, cc = (t & 15) * 4;
    #pragma unroll
    for (int i = 0; i < 4; ++i) {
        float4 v = *(const float4*)(xb + (size_t)(rr + i * 16) * 4096 + cc);
        *(float4*)&tile[rr + i * 16][cc] = v;
    }
    __syncthreads();
    int pr = t >> 2, io = (t & 3) * 16;
    __hip_bfloat16 obuf[16];
    #pragma unroll
    for (int j = 0; j < 16; ++j) obuf[j] = __float2bfloat16(tile[io + j][pr]);
    __hip_bfloat16* dst = xT + ((size_t)b * 4097 + p0 + pr) * 512 + ic0 + io;
    *(uint4*)dst       = *(uint4*)&obuf[0];
    *(uint4*)(dst + 8) = *(uint4*)&obuf[8];
}

// ------------- kernel 4: conv — A direct-global (reg ping-pong), B LDS ring-4 -------------
__global__ __launch_bounds__(512, 2) void conv_kernel(
    const __hip_bfloat16* __restrict__ xT,    // [16][4097][512]
    const __hip_bfloat16* __restrict__ wmod,  // [16*512][4608]
    const float* __restrict__ bias,
    float* __restrict__ out)                  // [16][512][4096]
{
    __shared__ __align__(16) __hip_bfloat16 Bsh[4][256 * 32];   // 64 KB

    const int t    = threadIdx.x;
    const int lane = t & 63;
    const int wid  = t >> 6;      // 0..7
    const int wm   = wid >> 2;    // 0..1 (M half: 128 oc rows)
    const int wn   = wid & 3;     // 0..3 (N quarter: 64 px)
    const int lr   = lane & 15;
    const int lq   = lane >> 4;

    // block decode: 512 blocks; per XCD 2 b's; oc-tile inner
    int bid = blockIdx.x;
    int xcd = bid & 7, idx = bid >> 3;
    int oc1 = idx & 1;
    int nt  = (idx >> 1) & 15;
    int bb  = (idx >> 5) & 1;
    int b   = xcd * 2 + bb;
    int oc0 = oc1 * 256, n0 = nt * 256;

    const __hip_bfloat16* wb = wmod + (size_t)(b * 512 + oc0) * KTOT;
    const __hip_bfloat16* xb = xT + (size_t)b * 4097 * 512;

    // B stage geometry (R11/R15-identical, verified 0 conflicts)
    const int qoff = (((t & 3) ^ ((t >> 3) & 3)) * 8);
    const int srow = t >> 2;                 // 0..127 (second slot: +128)
    const int p0g  = n0 + srow;
    const int y0p  = p0g >> 6, x0p = p0g & 63;

    // A direct-global per-lane fragment pointers: row = wm*128+mi*16+lr,
    // k-quad = lq*8. Within a tap, step offsets (ch*32 elems <= 1024B) fold
    // into the load's immediate field -> zero addressing VALU per step.
    const __hip_bfloat16* pAf[8];
    #pragma unroll
    for (int mi = 0; mi < 8; ++mi)
        pAf[mi] = wb + (size_t)(wm * 128 + mi * 16 + lr) * KTOT + lq * 8;

    // B fragment-read base with matching swizzle
    const int swq = (lq ^ ((lr >> 1) & 3)) * 8;
    const int brb = (wn * 64 + lr) * 32 + swq;

    f32x4 acc[8][4] = {};                 // 128 AGPR
    bf16x8 aP[2][8];                      // 64 VGPR ping-pong

    // per-tap B stage pointers (pixel shifted by (dy,dx); OOB -> zero row)
    const __hip_bfloat16 *pB0, *pB1, *nB0, *nB1;
    auto bptrs = [&](int tap, const __hip_bfloat16*& P0, const __hip_bfloat16*& P1) {
        int dy = tap / 3 - 1, dx = tap % 3 - 1;
        int sy = y0p + dy, sx = x0p + dx;
        int pix0 = ((((unsigned)sy)  < 64u) & (((unsigned)sx) < 64u)) ? ((sy  << 6) + sx) : 4096;
        int sy1 = sy + 2;   // second slot is +128 pixels = +2 image rows
        int pix1 = ((((unsigned)sy1) < 64u) & (((unsigned)sx) < 64u)) ? ((sy1 << 6) + sx) : 4096;
        P0 = xb + (size_t)pix0 * 512 + qoff;
        P1 = xb + (size_t)pix1 * 512 + qoff;
    };

#define STAGE_B(SB, Q0, Q1, OFF) { \
    GLL16((Q0) + (OFF), &Bsh[SB][t * 8]); \
    GLL16((Q1) + (OFF), &Bsh[SB][(t + 512) * 8]); }

// Step kk = tap*16+CH (parities/slots depend on CH only: 16%4==0).
// Ledger: at step top outstanding = [B(kk+1)x2 (survived prev vmw), A(kk)x8,
// B(kk+2)x2] = 12 -> vmw<2> completes B(kk+1) and A(kk); barrier at step end
// publishes B(kk+1) for next step's LDS reads.
#define STEP(CH, VN, DO_VMW, DO_A, DO_B, BQ0, BQ1, BOFF, DO_BAR) { \
    if (DO_VMW) { vmw<VN>(); } \
    if (DO_A) { \
        _Pragma("unroll") for (int mi = 0; mi < 8; ++mi) \
            aP[((CH) + 1) & 1][mi] = *(const bf16x8*)(pAf[mi] + ((CH) + 1) * 32); \
    } \
    if (DO_B) { STAGE_B(((CH) + 3) & 3, BQ0, BQ1, BOFF); } \
    { \
        bf16x8 bv[4]; \
        _Pragma("unroll") for (int ni = 0; ni < 4; ++ni) \
            bv[ni] = *(const bf16x8*)(&Bsh[(CH) & 3][brb + ni * 512]); \
        __builtin_amdgcn_s_setprio(1); \
        _Pragma("unroll") for (int mi = 0; mi < 8; ++mi) \
            _Pragma("unroll") for (int ni = 0; ni < 4; ++ni) \
                acc[mi][ni] = MFMA1(aP[(CH) & 1][mi], bv[ni], acc[mi][ni]); \
        __builtin_amdgcn_s_setprio(0); \
    } \
    if (DO_BAR) { BAR(); } }

    // ---- prologue: stage B(0,1,2); load A(0); B(0) resident ----
    bptrs(0, pB0, pB1);
    STAGE_B(0, pB0, pB1, 0);
    STAGE_B(1, pB0, pB1, 32);
    STAGE_B(2, pB0, pB1, 64);
    #pragma unroll
    for (int mi = 0; mi < 8; ++mi)
        aP[0][mi] = *(const bf16x8*)(pAf[mi]);
    vmw<12>();          // B(0) done; B(1),B(2),A(0) may fly (A dep-waited by compiler)
    BAR();

    for (int tap = 0; tap < 9; ++tap) {
        const bool last = (tap == 8);
        if (!last) bptrs(tap + 1, nB0, nB1);
        STEP(0,  2, true, true, true, pB0, pB1,  3 * 32, true);
        STEP(1,  2, true, true, true, pB0, pB1,  4 * 32, true);
        STEP(2,  2, true, true, true, pB0, pB1,  5 * 32, true);
        STEP(3,  2, true, true, true, pB0, pB1,  6 * 32, true);
        STEP(4,  2, true, true, true, pB0, pB1,  7 * 32, true);
        STEP(5,  2, true, true, true, pB0, pB1,  8 * 32, true);
        STEP(6,  2, true, true, true, pB0, pB1,  9 * 32, true);
        STEP(7,  2, true, true, true, pB0, pB1, 10 * 32, true);
        STEP(8,  2, true, true, true, pB0, pB1, 11 * 32, true);
        STEP(9,  2, true, true, true, pB0, pB1, 12 * 32, true);
        STEP(10, 2, true, true, true, pB0, pB1, 13 * 32, true);
        STEP(11, 2, true, true, true, pB0, pB1, 14 * 32, true);
        STEP(12, 2, true, true, true, pB0, pB1, 15 * 32, true);
        if (!last) {
            STEP(13, 2, true, true, true, nB0, nB1,  0, true);
            STEP(14, 2, true, true, true, nB0, nB1, 32, true);
            STEP(15, 2, true, true, true, nB0, nB1, 64, true);
            #pragma unroll
            for (int mi = 0; mi < 8; ++mi) pAf[mi] += 512;
            pB0 = nB0; pB1 = nB1;
        } else {
            // kk=141: A(142) prefetch, no B stage
            STEP(13, 2, true, true, false, pB0, pB1, 0, true);
            // kk=142: drain all; LOAD A(143) (R16's missing load — the fix)
            STEP(14, 0, true, true, false, pB0, pB1, 0, true);
            // kk=143: bare final step (aP[1]=A(143), compiler dep-waits)
            STEP(15, 0, false, false, false, pB0, pB1, 0, false);
        }
    }
#undef STEP
#undef STAGE_B

    // ---- epilogue ----
    #pragma unroll
    for (int mi = 0; mi < 8; ++mi) {
        int oc = oc0 + wm * 128 + mi * 16 + lq * 4;
        #pragma unroll
        for (int ni = 0; ni < 4; ++ni) {
            int n = n0 + wn * 64 + ni * 16 + lr;
            #pragma unroll
            for (int v = 0; v < 4; ++v) {
                float r = acc[mi][ni][v] + bias[oc + v];
                out[((size_t)(b * OC + oc + v)) * HW + n] = r;
            }
        }
    }
}

extern "C" void kernel_launch(void* const* d_in, const int* in_sizes, int n_in,
                              void* d_out, int out_size, void* d_ws, size_t ws_size,
                              hipStream_t stream) {
    const float* x      = (const float*)d_in[0];
    const float* style  = (const float*)d_in[1];
    const float* weight = (const float*)d_in[2];
    const float* bias   = (const float*)d_in[3];
    const float* mod_w  = (const float*)d_in[4];
    const float* mod_b  = (const float*)d_in[5];
    float* out = (float*)d_out;

    // ws: s [32KB] | wmod bf16 [75.5MB] | xT bf16 [67.2MB]
    float* s_ws = (float*)d_ws;
    __hip_bfloat16* wmod = (__hip_bfloat16*)((char*)d_ws + 32768);
    __hip_bfloat16* xT   = (__hip_bfloat16*)((char*)d_ws + 32768 + (size_t)16 * 512 * KTOT * 2);

    style_mod_kernel<<<2048, 256, 0, stream>>>(style, mod_w, mod_b, s_ws);
    wmod_kernel<<<512, 256, 0, stream>>>(weight, s_ws, wmod);
    zero_row_kernel<<<16, 256, 0, stream>>>(xT);
    dim3 tgrid(64, 8, 16);
    xpose_kernel<<<tgrid, 256, 0, stream>>>(x, xT);
    conv_kernel<<<512, 512, 0, stream>>>(xT, wmod, bias, out);
}